// Round 7
// baseline (261.882 us; speedup 1.0000x reference)
//
#include <hip/hip_runtime.h>
#include <stdint.h>

#define N_NODES 50000
#define N_EDGES 800000
#define H_DIM 128
#define N_REL 40
#define N_BASES 4
#define N_RANGES 196         // node ranges of 256
#define EDGES_PER_BLK 4000

typedef __attribute__((ext_vector_type(8))) short bf16x8;
typedef __attribute__((ext_vector_type(4))) float f32x4;

// round-to-nearest-even f32 -> bf16 bits
__device__ __forceinline__ unsigned short f2bf(float f) {
    unsigned int u = __float_as_uint(f);
    unsigned int r = u + 0x7fffu + ((u >> 16) & 1u);
    return (unsigned short)(r >> 16);
}

// ---------------------------------------------------------------------------
// K-1: zero the per-node degree counters (workspace is poisoned each iter).
__global__ __launch_bounds__(512) void zero_deg(int* __restrict__ deg) {
    int i = blockIdx.x * 512 + threadIdx.x;
    if (i < N_NODES) deg[i] = 0;
}

// ---------------------------------------------------------------------------
// K0 "prep" (fused): blocks 0..3124   -> cast h into A (bf16, stride 128)
//                    blocks 3125..3129 -> repack weights into frag-major wt3
//                    blocks 3130..3329 -> edge pack (pkd) + per-node degree
//                                         count via global atomics (L2-side).
//                                         Block 3130 zeroes the 16-entry pad.
// pkd[e] = { src | etype<<20 , dst | nbf<<17 }  (nbf = bf16 of norm >= 0)
__global__ __launch_bounds__(256) void prep_kernel(
        const float* __restrict__ h,
        const float* __restrict__ basis_w, const float* __restrict__ loop_w,
        const int* __restrict__ src, const int* __restrict__ dst,
        const int* __restrict__ etype, const float* __restrict__ norm,
        unsigned short* __restrict__ A, unsigned short* __restrict__ wt3,
        uint2* __restrict__ pkd, int* __restrict__ deg,
        unsigned* __restrict__ sorted_src, float4* __restrict__ sorted_cf) {
    int bid = blockIdx.x;
    if (bid < 3125) {
        int t = bid * 256 + threadIdx.x;        // [0, 800000)
        int row = t >> 4;
        int cb = (t & 15) * 8;
        const float* p = h + (size_t)row * 128 + cb;
        float4 a0 = ((const float4*)p)[0];
        float4 a1 = ((const float4*)p)[1];
        bf16x8 o;
        o[0] = (short)f2bf(a0.x); o[1] = (short)f2bf(a0.y);
        o[2] = (short)f2bf(a0.z); o[3] = (short)f2bf(a0.w);
        o[4] = (short)f2bf(a1.x); o[5] = (short)f2bf(a1.y);
        o[6] = (short)f2bf(a1.z); o[7] = (short)f2bf(a1.w);
        *(bf16x8*)(A + (size_t)row * H_DIM + cb) = o;
    } else if (bid < 3130) {
        int mat = bid - 3125;                   // 0..3 basis, 4 loop
        const float* srcm = (mat < 4) ? (basis_w + mat * 16384) : loop_w;
        int koff = (mat < 4) ? (128 + mat * 128) : 0;
        int t = threadIdx.x;
#pragma unroll
        for (int i = 0; i < 16; ++i) {
            int f = t + i * 256;                // [0,4096) float4 index
            int k = f >> 5;
            int j4 = (f & 31) * 4;
            float4 v = ((const float4*)srcm)[f];
            int kg = koff + k;
            int ks = kg >> 5;
            int quad = (kg >> 3) & 3;
            int jj = kg & 7;
            float vv[4] = {v.x, v.y, v.z, v.w};
#pragma unroll
            for (int d = 0; d < 4; ++d) {
                int j = j4 + d;
                int cg = j >> 4;
                int n16 = j & 15;
                wt3[(size_t)((ks * 8 + cg) * 64 + quad * 16 + n16) * 8 + jj] =
                    f2bf(vv[d]);
            }
        }
    } else {
        int blk = bid - 3130;                   // 0..199
        int t = threadIdx.x;
        if (blk == 0 && t >= 240) {             // zero over-read pad
            int k = t - 240;                    // 0..15
            sorted_src[N_EDGES + k] = 0u;
            sorted_cf[N_EDGES + k] = make_float4(0.f, 0.f, 0.f, 0.f);
        }
        int e0 = blk * EDGES_PER_BLK;
        for (int i = t; i < EDGES_PER_BLK; i += 256) {
            int e = e0 + i;
            int d = dst[e];
            unsigned int nbf = f2bf(norm[e]);   // <= 0x7FFF (norm >= 0)
            pkd[e] = make_uint2((unsigned)src[e] | ((unsigned)etype[e] << 20),
                                (unsigned)d | (nbf << 17));
            atomicAdd(&deg[d], 1);
        }
    }
}

// K1: scan_offs (196 blocks x 512). Block r:
//  Phase A: base = sum(deg[0 .. r*256)) via 512-wide coalesced strided sum
//           + wave shuffle-reduce + LDS combine (<=200KB L2 reads/block).
//  Phase B: 256-wide shuffle scan of this range's degrees -> offs and cur.
__global__ __launch_bounds__(512) void scan_offs(
        const int* __restrict__ deg, int* __restrict__ offs,
        int* __restrict__ cur) {
    __shared__ int red[8];
    __shared__ int wsum[4];
    int r = blockIdx.x;
    int t = threadIdx.x, lane = t & 63, w = t >> 6;
    // Phase A
    int lim = r * 256;
    int s = 0;
    for (int i = t; i < lim; i += 512) s += deg[i];
#pragma unroll
    for (int d = 32; d; d >>= 1) s += __shfl_down(s, d);
    if (lane == 0) red[w] = s;
    __syncthreads();
    int base = 0;
#pragma unroll
    for (int ww = 0; ww < 8; ++ww) base += red[ww];
    // Phase B (threads 0..255)
    int node = r * 256 + t;
    int x = 0;
    if (t < 256) x = (node < N_NODES) ? deg[node] : 0;
    int v = x;
#pragma unroll
    for (int d = 1; d < 64; d <<= 1) {
        int y = __shfl_up(v, d);
        if (lane >= d) v += y;
    }
    if (t < 256 && lane == 63) wsum[w] = v;
    __syncthreads();
    if (t < 256) {
        int wpre = 0;
        if (w > 0) wpre += wsum[0];
        if (w > 1) wpre += wsum[1];
        if (w > 2) wpre += wsum[2];
        int excl = base + wpre + v - x;
        if (node < N_NODES) {
            offs[node] = excl;
            cur[node] = excl;
        }
    }
    if (r == N_RANGES - 1 && t == 0) offs[N_NODES] = N_EDGES;
}

// K2: scatter (3125 blocks x 256, one edge per thread). Direct counting-sort
// placement: pos = atomicAdd(cur[dst]); write src index + precomputed
// cf = w_comp[etype]*norm. Replaces the two low-occupancy sort kernels.
__global__ __launch_bounds__(256) void scatter_kernel(
        const uint2* __restrict__ pkd, const float* __restrict__ w_comp,
        int* __restrict__ cur, unsigned* __restrict__ sorted_src,
        float4* __restrict__ sorted_cf) {
    int e = blockIdx.x * 256 + threadIdx.x;
    if (e >= N_EDGES) return;
    uint2 p = pkd[e];
    int d = p.y & 0x1FFFF;
    float nm = __uint_as_float((p.y >> 17) << 16);
    float4 wc = ((const float4*)w_comp)[p.x >> 20];
    int pos = atomicAdd(&cur[d], 1);
    sorted_src[pos] = p.x & 0xFFFFF;
    sorted_cf[pos] = make_float4(wc.x * nm, wc.y * nm, wc.z * nm, wc.w * nm);
}

// K3 (fused aggregate + GEMM), static grid 1563, 512 threads / 8 waves,
// 32-node tile. Round-5 structure with ONE change: the edge loop is a 2-deep
// ping-pong — batch n+1's {ssrc s_loads, 8 gathers} are issued before batch
// n's FMAs, so gather latency hides under compute (16 outstanding loads/wave
// at peak). Named A/B buffers only (no runtime-indexed arrays -> no scratch).
// cf stays single-buffered scalar (SGPR ~90 < 102; VGPR ~36 < 64 cap).
// Phase 2 unchanged: 32x128x640 bf16 MFMA from XOR-swizzled LDS.
__global__ __launch_bounds__(512, 8) void agg_gemm(
        const int* __restrict__ offs, const unsigned* __restrict__ ssrc,
        const float4* __restrict__ scf,
        const unsigned short* __restrict__ Ab,
        const unsigned short* __restrict__ wt3,
        const float* __restrict__ bias, float* __restrict__ out) {
    __shared__ __align__(16) unsigned short S[32 * 640];   // 40 KB
    int wv = threadIdx.x >> 6;
    int lane = threadIdx.x & 63;
    int nbase = blockIdx.x * 32;
    const unsigned int* Au = (const unsigned int*)Ab;

#define CONSUME(U, JJ) do {                                                  \
        float4 c[8];                                                         \
        int rem = end - (JJ);                                                \
        _Pragma("unroll")                                                    \
        for (int k = 0; k < 8; ++k) c[k] = scf[(JJ) + k];                    \
        if (rem < 8) {                                                       \
            _Pragma("unroll")                                                \
            for (int k = 0; k < 8; ++k)                                      \
                if (k >= rem) c[k] = make_float4(0.f, 0.f, 0.f, 0.f);        \
        }                                                                    \
        _Pragma("unroll")                                                    \
        for (int k = 0; k < 8; ++k) {                                        \
            float lo = __uint_as_float(U[k] << 16);                          \
            float hi = __uint_as_float(U[k] & 0xffff0000u);                  \
            a0l += c[k].x * lo; a0h += c[k].x * hi;                          \
            a1l += c[k].y * lo; a1h += c[k].y * hi;                          \
            a2l += c[k].z * lo; a2h += c[k].z * hi;                          \
            a3l += c[k].w * lo; a3h += c[k].w * hi;                          \
        }                                                                    \
    } while (0)

#pragma unroll
    for (int q = 0; q < 4; ++q) {
        int row = (wv << 2) + q;
        int v = __builtin_amdgcn_readfirstlane(nbase + row);
        float a0l = 0.f, a0h = 0.f, a1l = 0.f, a1h = 0.f;
        float a2l = 0.f, a2h = 0.f, a3l = 0.f, a3h = 0.f;
        unsigned int hb = 0u;
        if (v < N_NODES) {
            hb = Au[(size_t)v * 64 + lane];     // own hbf row (cols 2l,2l+1)
            int begin = __builtin_amdgcn_readfirstlane(offs[v]);
            int end   = __builtin_amdgcn_readfirstlane(offs[v + 1]);
            if (begin < end) {
                unsigned suA[8], suB[8], uA[8], uB[8];
                int jA = begin, jB = 0;
#pragma unroll
                for (int k = 0; k < 8; ++k) suA[k] = ssrc[jA + k];
#pragma unroll
                for (int k = 0; k < 8; ++k)
                    uA[k] = Au[(size_t)suA[k] * 64 + lane];
                int curA = 1;
                for (int jn = begin + 8; jn < end; jn += 8) {
                    if (curA) {
                        jB = jn;
#pragma unroll
                        for (int k = 0; k < 8; ++k) suB[k] = ssrc[jB + k];
#pragma unroll
                        for (int k = 0; k < 8; ++k)
                            uB[k] = Au[(size_t)suB[k] * 64 + lane];
                        CONSUME(uA, jA);
                    } else {
                        jA = jn;
#pragma unroll
                        for (int k = 0; k < 8; ++k) suA[k] = ssrc[jA + k];
#pragma unroll
                        for (int k = 0; k < 8; ++k)
                            uA[k] = Au[(size_t)suA[k] * 64 + lane];
                        CONSUME(uB, jB);
                    }
                    curA ^= 1;
                }
                if (curA) CONSUME(uA, jA);
                else      CONSUME(uB, jB);
            }
        }
        // stage row into LDS: [hbf(256B) | S0 | S1 | S2 | S3], swizzled
        char* rp = (char*)S + row * 1280;
        int swz = (row & 7) << 4;
        *(unsigned int*)(rp + ((lane * 4) ^ swz)) = hb;
        *(unsigned int*)(rp + ((256 + lane * 4) ^ swz)) =
            (unsigned int)f2bf(a0l) | ((unsigned int)f2bf(a0h) << 16);
        *(unsigned int*)(rp + ((512 + lane * 4) ^ swz)) =
            (unsigned int)f2bf(a1l) | ((unsigned int)f2bf(a1h) << 16);
        *(unsigned int*)(rp + ((768 + lane * 4) ^ swz)) =
            (unsigned int)f2bf(a2l) | ((unsigned int)f2bf(a2h) << 16);
        *(unsigned int*)(rp + ((1024 + lane * 4) ^ swz)) =
            (unsigned int)f2bf(a3l) | ((unsigned int)f2bf(a3h) << 16);
    }
#undef CONSUME
    __syncthreads();

    // Phase 2: rows 0..31 of LDS tile, wave wv covers cols [wv*16, wv*16+16)
    int n16 = lane & 15;
    int quad = lane >> 4;
    f32x4 acc0 = (f32x4)0.f, acc1 = (f32x4)0.f;

    const char* s0p = (const char*)S + n16 * 1280;
    const char* s1p = s0p + 16 * 1280;
    int swz2 = (n16 & 7) << 4;
    const unsigned short* bwp = wt3 + (size_t)wv * 512 + (size_t)lane * 8;

#pragma unroll
    for (int ks = 0; ks < 20; ++ks) {
        int off = (ks * 64 + quad * 16) ^ swz2;
        bf16x8 a0 = *(const bf16x8*)(s0p + off);
        bf16x8 a1 = *(const bf16x8*)(s1p + off);
        bf16x8 b  = *(const bf16x8*)(bwp + (size_t)ks * 4096);
        acc0 = __builtin_amdgcn_mfma_f32_16x16x32_bf16(a0, b, acc0, 0, 0, 0);
        acc1 = __builtin_amdgcn_mfma_f32_16x16x32_bf16(a1, b, acc1, 0, 0, 0);
    }

    // C/D layout: col = lane&15, row = quad*4 + reg
    int col = (wv << 4) + n16;
    float bv = bias[col];
#pragma unroll
    for (int rg = 0; rg < 4; ++rg) {
        int r0 = nbase + quad * 4 + rg;
        if (r0 < N_NODES)
            out[(size_t)r0 * H_DIM + col] = fmaxf(acc0[rg] + bv, 0.f);
        int r1 = nbase + 16 + quad * 4 + rg;
        if (r1 < N_NODES)
            out[(size_t)r1 * H_DIM + col] = fmaxf(acc1[rg] + bv, 0.f);
    }
}

extern "C" void kernel_launch(void* const* d_in, const int* in_sizes, int n_in,
                              void* d_out, int out_size, void* d_ws, size_t ws_size,
                              hipStream_t stream) {
    const float* h       = (const float*)d_in[0];
    const float* norm    = (const float*)d_in[1];
    const float* basis_w = (const float*)d_in[2];
    const float* w_comp  = (const float*)d_in[3];
    const float* loop_w  = (const float*)d_in[4];
    const float* bias    = (const float*)d_in[5];
    const int*   src     = (const int*)d_in[6];
    const int*   dst     = (const int*)d_in[7];
    const int*   etype   = (const int*)d_in[8];
    float* out = (float*)d_out;

    // ws layout (bytes):
    char* base = (char*)d_ws;
    unsigned short* wt3       = (unsigned short*)(base + 0);          //    163,840
    unsigned short* A         = (unsigned short*)(base + 163840);     // 12,800,000
    int*            offs      = (int*)(base + 12963840);              //    200,004
    uint2*          pkd       = (uint2*)(base + 13163848);            //  6,400,000
    float4*         sorted_cf = (float4*)(base + 19563856);           // 12,800,256
    unsigned*       sorted_src= (unsigned*)(base + 32364112);         //  3,200,064
    int*            deg       = (int*)(base + 35564176);              //    200,000
    int*            cur       = (int*)(base + 35764176);              //    200,000
    // total ~36.0 MB

    zero_deg<<<98, 512, 0, stream>>>(deg);
    prep_kernel<<<3330, 256, 0, stream>>>(h, basis_w, loop_w,
                                          src, dst, etype, norm,
                                          A, wt3, pkd, deg,
                                          sorted_src, sorted_cf);
    scan_offs<<<N_RANGES, 512, 0, stream>>>(deg, offs, cur);
    scatter_kernel<<<3125, 256, 0, stream>>>(pkd, w_comp, cur,
                                             sorted_src, sorted_cf);
    agg_gemm<<<1563, 512, 0, stream>>>(offs, sorted_src, sorted_cf,
                                       A, wt3, bias, out);
}

// Round 8
// 183.773 us; speedup vs baseline: 1.4250x; 1.4250x over previous
//
#include <hip/hip_runtime.h>
#include <stdint.h>

#define N_NODES 50000
#define N_EDGES 800000
#define H_DIM 128
#define N_REL 40
#define N_BASES 4
#define N_RANGES 196         // node ranges of 256 (dst >> 8)
#define EP_BLOCKS 200        // edge chunks of 4000
#define EDGES_PER_BLK 4000
#define STAGE_CAP 5120       // LDS staging capacity for bucket_sort

typedef __attribute__((ext_vector_type(8))) short bf16x8;
typedef __attribute__((ext_vector_type(4))) float f32x4;

// round-to-nearest-even f32 -> bf16 bits
__device__ __forceinline__ unsigned short f2bf(float f) {
    unsigned int u = __float_as_uint(f);
    unsigned int r = u + 0x7fffu + ((u >> 16) & 1u);
    return (unsigned short)(r >> 16);
}

// ---------------------------------------------------------------------------
// K0 "prep" (fused): blocks 0..3124   -> cast h into A (bf16, stride 128)
//                    blocks 3125..3129 -> repack weights into frag-major wt3
//                    blocks 3130..3329 -> edge pack (pkd) + per-(block,bucket)
//                                         histogram into gcnt[blk][range]
//                                         (LDS atomics ONLY — device atomics
//                                          were a 70us stall, round 7).
// pkd[e] = { src | etype<<20 , dst | nbf<<17 }  (nbf = bf16 of norm >= 0)
__global__ __launch_bounds__(256) void prep_kernel(
        const float* __restrict__ h,
        const float* __restrict__ basis_w, const float* __restrict__ loop_w,
        const int* __restrict__ src, const int* __restrict__ dst,
        const int* __restrict__ etype, const float* __restrict__ norm,
        unsigned short* __restrict__ A, unsigned short* __restrict__ wt3,
        uint2* __restrict__ pkd, int* __restrict__ gcnt,
        unsigned* __restrict__ sorted_src, float4* __restrict__ sorted_cf) {
    int bid = blockIdx.x;
    if (bid < 3125) {
        int t = bid * 256 + threadIdx.x;        // [0, 800000)
        int row = t >> 4;
        int cb = (t & 15) * 8;
        const float* p = h + (size_t)row * 128 + cb;
        float4 a0 = ((const float4*)p)[0];
        float4 a1 = ((const float4*)p)[1];
        bf16x8 o;
        o[0] = (short)f2bf(a0.x); o[1] = (short)f2bf(a0.y);
        o[2] = (short)f2bf(a0.z); o[3] = (short)f2bf(a0.w);
        o[4] = (short)f2bf(a1.x); o[5] = (short)f2bf(a1.y);
        o[6] = (short)f2bf(a1.z); o[7] = (short)f2bf(a1.w);
        *(bf16x8*)(A + (size_t)row * H_DIM + cb) = o;
    } else if (bid < 3130) {
        int mat = bid - 3125;                   // 0..3 basis, 4 loop
        const float* srcm = (mat < 4) ? (basis_w + mat * 16384) : loop_w;
        int koff = (mat < 4) ? (128 + mat * 128) : 0;
        int t = threadIdx.x;
#pragma unroll
        for (int i = 0; i < 16; ++i) {
            int f = t + i * 256;                // [0,4096) float4 index
            int k = f >> 5;
            int j4 = (f & 31) * 4;
            float4 v = ((const float4*)srcm)[f];
            int kg = koff + k;
            int ks = kg >> 5;
            int quad = (kg >> 3) & 3;
            int jj = kg & 7;
            float vv[4] = {v.x, v.y, v.z, v.w};
#pragma unroll
            for (int d = 0; d < 4; ++d) {
                int j = j4 + d;
                int cg = j >> 4;
                int n16 = j & 15;
                wt3[(size_t)((ks * 8 + cg) * 64 + quad * 16 + n16) * 8 + jj] =
                    f2bf(vv[d]);
            }
        }
    } else {
        __shared__ int lhist[N_RANGES];
        int blk = bid - 3130;                   // 0..199
        int t = threadIdx.x;
        if (t < N_RANGES) lhist[t] = 0;
        if (blk == 0 && t >= 240) {             // zero over-read pad
            int k = t - 240;                    // 0..15
            sorted_src[N_EDGES + k] = 0u;
            sorted_cf[N_EDGES + k] = make_float4(0.f, 0.f, 0.f, 0.f);
        }
        __syncthreads();
        int e0 = blk * EDGES_PER_BLK;
        for (int i = t; i < EDGES_PER_BLK; i += 256) {
            int e = e0 + i;
            int d = dst[e];
            unsigned int nbf = f2bf(norm[e]);   // <= 0x7FFF (norm >= 0)
            pkd[e] = make_uint2((unsigned)src[e] | ((unsigned)etype[e] << 20),
                                (unsigned)d | (nbf << 17));
            atomicAdd(&lhist[d >> 8], 1);
        }
        __syncthreads();
        if (t < N_RANGES) gcnt[blk * N_RANGES + t] = lhist[t];
    }
}

// K1: binscatter (512 threads). Block b places its 4000 edges into
// bucket-grouped order. Bases computed ENTIRELY in-block: thread t<196
// column-sums gcnt[bb][t] over all 200 bb (coalesced, L2-resident 153KB)
// tracking both full total and prefix below b, then a 196-wide shuffle scan
// of totals gives bstart; cursor = bstart + pre.
__global__ __launch_bounds__(512) void binscatter(
        const uint2* __restrict__ pkd, const int* __restrict__ gcnt,
        uint2* __restrict__ bucketed) {
    __shared__ int lcur[N_RANGES];
    __shared__ int wsum[8];
    int t = threadIdx.x, lane = t & 63, w = t >> 6;
    int b = blockIdx.x;
    int tot = 0, pre = 0;
    if (t < N_RANGES) {
        for (int bb = 0; bb < EP_BLOCKS; ++bb) {
            int g = gcnt[bb * N_RANGES + t];
            tot += g;
            if (bb < b) pre += g;
        }
    }
    int x = (t < N_RANGES) ? tot : 0;
    int v = x;
#pragma unroll
    for (int d = 1; d < 64; d <<= 1) {
        int y = __shfl_up(v, d);
        if (lane >= d) v += y;
    }
    if (lane == 63) wsum[w] = v;
    __syncthreads();
    int wpre = 0;
#pragma unroll
    for (int ww = 0; ww < 7; ++ww)
        if (w > ww) wpre += wsum[ww];
    if (t < N_RANGES)
        lcur[t] = (wpre + v - x) + pre;         // bstart[t] + blk-prefix
    __syncthreads();
    int e0 = b * EDGES_PER_BLK;
    for (int i = t; i < EDGES_PER_BLK; i += 512) {
        uint2 p = pkd[e0 + i];
        int r = (p.y & 0x1FFFF) >> 8;
        int pos = atomicAdd(&lcur[r], 1);
        bucketed[pos] = p;
    }
}

// K2: bucket_sort (512 threads). One block per bucket; begin/end computed
// in-block from gcnt column sums + 196-wide scan.
// Pass 1: LDS per-dst histogram -> scan -> per-dst offsets (offs coalesced).
// Pass 2: place edges into LDS stage by exact sorted position, stream out
// coalesced as sorted_src (u32) + sorted_cf (float4 = w_comp[etype]*norm).
__global__ __launch_bounds__(512) void bucket_sort(
        const int* __restrict__ gcnt, const uint2* __restrict__ bucketed,
        const float* __restrict__ w_comp,
        unsigned* __restrict__ sorted_src, float4* __restrict__ sorted_cf,
        int* __restrict__ offs) {
    __shared__ int hist[256];
    __shared__ int cur[256];
    __shared__ int wsum[8];
    __shared__ int sbeg;
    __shared__ int stot;
    __shared__ uint2 stage[STAGE_CAP];
    int r = blockIdx.x;
    int t = threadIdx.x, lane = t & 63, w = t >> 6;
    int tot = 0;
    if (t < N_RANGES)
        for (int bb = 0; bb < EP_BLOCKS; ++bb)
            tot += gcnt[bb * N_RANGES + t];
    int x = (t < N_RANGES) ? tot : 0;
    int v = x;
#pragma unroll
    for (int d = 1; d < 64; d <<= 1) {
        int y = __shfl_up(v, d);
        if (lane >= d) v += y;
    }
    if (lane == 63) wsum[w] = v;
    if (t < 256) hist[t] = 0;
    __syncthreads();
    int wpre = 0;
#pragma unroll
    for (int ww = 0; ww < 7; ++ww)
        if (w > ww) wpre += wsum[ww];
    if (t == r) { sbeg = wpre + v - x; stot = x; }
    __syncthreads();
    int begin = sbeg;
    int end = begin + stot;
    int n = end - begin;
    for (int i = begin + t; i < end; i += 512)
        atomicAdd(&hist[bucketed[i].y & 255], 1);
    __syncthreads();
    int x2 = (t < 256) ? hist[t] : 0;
    int v2 = x2;
#pragma unroll
    for (int d = 1; d < 64; d <<= 1) {
        int y = __shfl_up(v2, d);
        if (lane >= d) v2 += y;
    }
    if (lane == 63) wsum[w] = v2;
    __syncthreads();
    int wpre2 = 0;
#pragma unroll
    for (int ww = 0; ww < 3; ++ww)          // only waves 0..3 hold hist
        if (w > ww) wpre2 += wsum[ww];
    if (t < 256) {
        int excl_rel = wpre2 + v2 - x2;     // position within the region
        int node = r * 256 + t;
        if (node < N_NODES) offs[node] = begin + excl_rel;
        cur[t] = excl_rel;
    }
    if (r == N_RANGES - 1 && t == 0) offs[N_NODES] = N_EDGES;
    __syncthreads();
    if (n <= STAGE_CAP) {
        for (int i = begin + t; i < end; i += 512) {
            uint2 p = bucketed[i];
            int pos = atomicAdd(&cur[p.y & 255], 1);
            stage[pos] = make_uint2(p.x, (p.y >> 17) << 16);
        }
        __syncthreads();
        for (int i = t; i < n; i += 512) {
            uint2 p = stage[i];
            float nm = __uint_as_float(p.y);
            float4 wc = ((const float4*)w_comp)[p.x >> 20];
            sorted_src[begin + i] = p.x & 0xFFFFF;
            sorted_cf[begin + i] =
                make_float4(wc.x * nm, wc.y * nm, wc.z * nm, wc.w * nm);
        }
    } else {                                    // pathological fallback
        for (int i = begin + t; i < end; i += 512) {
            uint2 p = bucketed[i];
            int pos = atomicAdd(&cur[p.y & 255], 1);
            float nm = __uint_as_float((p.y >> 17) << 16);
            float4 wc = ((const float4*)w_comp)[p.x >> 20];
            sorted_src[begin + pos] = p.x & 0xFFFFF;
            sorted_cf[begin + pos] =
                make_float4(wc.x * nm, wc.y * nm, wc.z * nm, wc.w * nm);
        }
    }
}

// K3 (fused aggregate + GEMM), static grid 1563, 512 threads / 8 waves,
// 32-node tile. Round-5 structure + 2-deep ping-pong on the gather batch:
// batch n+1's {ssrc loads, 8 gathers} issue before batch n's FMAs, so gather
// latency hides under compute (16 outstanding loads/wave at peak). Named A/B
// buffers only (no runtime-indexed arrays -> no scratch). Correctness of the
// masked tail verified in round 7 (passed, absmax unchanged).
// Phase 2 unchanged: 32x128x640 bf16 MFMA from XOR-swizzled LDS.
__global__ __launch_bounds__(512, 8) void agg_gemm(
        const int* __restrict__ offs, const unsigned* __restrict__ ssrc,
        const float4* __restrict__ scf,
        const unsigned short* __restrict__ Ab,
        const unsigned short* __restrict__ wt3,
        const float* __restrict__ bias, float* __restrict__ out) {
    __shared__ __align__(16) unsigned short S[32 * 640];   // 40 KB
    int wv = threadIdx.x >> 6;
    int lane = threadIdx.x & 63;
    int nbase = blockIdx.x * 32;
    const unsigned int* Au = (const unsigned int*)Ab;

#define CONSUME(U, JJ) do {                                                  \
        float4 c[8];                                                         \
        int rem = end - (JJ);                                                \
        _Pragma("unroll")                                                    \
        for (int k = 0; k < 8; ++k) c[k] = scf[(JJ) + k];                    \
        if (rem < 8) {                                                       \
            _Pragma("unroll")                                                \
            for (int k = 0; k < 8; ++k)                                      \
                if (k >= rem) c[k] = make_float4(0.f, 0.f, 0.f, 0.f);        \
        }                                                                    \
        _Pragma("unroll")                                                    \
        for (int k = 0; k < 8; ++k) {                                        \
            float lo = __uint_as_float(U[k] << 16);                          \
            float hi = __uint_as_float(U[k] & 0xffff0000u);                  \
            a0l += c[k].x * lo; a0h += c[k].x * hi;                          \
            a1l += c[k].y * lo; a1h += c[k].y * hi;                          \
            a2l += c[k].z * lo; a2h += c[k].z * hi;                          \
            a3l += c[k].w * lo; a3h += c[k].w * hi;                          \
        }                                                                    \
    } while (0)

#pragma unroll
    for (int q = 0; q < 4; ++q) {
        int row = (wv << 2) + q;
        int v = __builtin_amdgcn_readfirstlane(nbase + row);
        float a0l = 0.f, a0h = 0.f, a1l = 0.f, a1h = 0.f;
        float a2l = 0.f, a2h = 0.f, a3l = 0.f, a3h = 0.f;
        unsigned int hb = 0u;
        if (v < N_NODES) {
            hb = Au[(size_t)v * 64 + lane];     // own hbf row (cols 2l,2l+1)
            int begin = __builtin_amdgcn_readfirstlane(offs[v]);
            int end   = __builtin_amdgcn_readfirstlane(offs[v + 1]);
            if (begin < end) {
                unsigned suA[8], suB[8], uA[8], uB[8];
                int jA = begin, jB = 0;
#pragma unroll
                for (int k = 0; k < 8; ++k) suA[k] = ssrc[jA + k];
#pragma unroll
                for (int k = 0; k < 8; ++k)
                    uA[k] = Au[(size_t)suA[k] * 64 + lane];
                int curA = 1;
                for (int jn = begin + 8; jn < end; jn += 8) {
                    if (curA) {
                        jB = jn;
#pragma unroll
                        for (int k = 0; k < 8; ++k) suB[k] = ssrc[jB + k];
#pragma unroll
                        for (int k = 0; k < 8; ++k)
                            uB[k] = Au[(size_t)suB[k] * 64 + lane];
                        CONSUME(uA, jA);
                    } else {
                        jA = jn;
#pragma unroll
                        for (int k = 0; k < 8; ++k) suA[k] = ssrc[jA + k];
#pragma unroll
                        for (int k = 0; k < 8; ++k)
                            uA[k] = Au[(size_t)suA[k] * 64 + lane];
                        CONSUME(uB, jB);
                    }
                    curA ^= 1;
                }
                if (curA) CONSUME(uA, jA);
                else      CONSUME(uB, jB);
            }
        }
        // stage row into LDS: [hbf(256B) | S0 | S1 | S2 | S3], swizzled
        char* rp = (char*)S + row * 1280;
        int swz = (row & 7) << 4;
        *(unsigned int*)(rp + ((lane * 4) ^ swz)) = hb;
        *(unsigned int*)(rp + ((256 + lane * 4) ^ swz)) =
            (unsigned int)f2bf(a0l) | ((unsigned int)f2bf(a0h) << 16);
        *(unsigned int*)(rp + ((512 + lane * 4) ^ swz)) =
            (unsigned int)f2bf(a1l) | ((unsigned int)f2bf(a1h) << 16);
        *(unsigned int*)(rp + ((768 + lane * 4) ^ swz)) =
            (unsigned int)f2bf(a2l) | ((unsigned int)f2bf(a2h) << 16);
        *(unsigned int*)(rp + ((1024 + lane * 4) ^ swz)) =
            (unsigned int)f2bf(a3l) | ((unsigned int)f2bf(a3h) << 16);
    }
#undef CONSUME
    __syncthreads();

    // Phase 2: rows 0..31 of LDS tile, wave wv covers cols [wv*16, wv*16+16)
    int n16 = lane & 15;
    int quad = lane >> 4;
    f32x4 acc0 = (f32x4)0.f, acc1 = (f32x4)0.f;

    const char* s0p = (const char*)S + n16 * 1280;
    const char* s1p = s0p + 16 * 1280;
    int swz2 = (n16 & 7) << 4;
    const unsigned short* bwp = wt3 + (size_t)wv * 512 + (size_t)lane * 8;

#pragma unroll
    for (int ks = 0; ks < 20; ++ks) {
        int off = (ks * 64 + quad * 16) ^ swz2;
        bf16x8 a0 = *(const bf16x8*)(s0p + off);
        bf16x8 a1 = *(const bf16x8*)(s1p + off);
        bf16x8 b  = *(const bf16x8*)(bwp + (size_t)ks * 4096);
        acc0 = __builtin_amdgcn_mfma_f32_16x16x32_bf16(a0, b, acc0, 0, 0, 0);
        acc1 = __builtin_amdgcn_mfma_f32_16x16x32_bf16(a1, b, acc1, 0, 0, 0);
    }

    // C/D layout: col = lane&15, row = quad*4 + reg
    int col = (wv << 4) + n16;
    float bv = bias[col];
#pragma unroll
    for (int rg = 0; rg < 4; ++rg) {
        int r0 = nbase + quad * 4 + rg;
        if (r0 < N_NODES)
            out[(size_t)r0 * H_DIM + col] = fmaxf(acc0[rg] + bv, 0.f);
        int r1 = nbase + 16 + quad * 4 + rg;
        if (r1 < N_NODES)
            out[(size_t)r1 * H_DIM + col] = fmaxf(acc1[rg] + bv, 0.f);
    }
}

extern "C" void kernel_launch(void* const* d_in, const int* in_sizes, int n_in,
                              void* d_out, int out_size, void* d_ws, size_t ws_size,
                              hipStream_t stream) {
    const float* h       = (const float*)d_in[0];
    const float* norm    = (const float*)d_in[1];
    const float* basis_w = (const float*)d_in[2];
    const float* w_comp  = (const float*)d_in[3];
    const float* loop_w  = (const float*)d_in[4];
    const float* bias    = (const float*)d_in[5];
    const int*   src     = (const int*)d_in[6];
    const int*   dst     = (const int*)d_in[7];
    const int*   etype   = (const int*)d_in[8];
    float* out = (float*)d_out;

    // ws layout (bytes):
    char* base = (char*)d_ws;
    unsigned short* wt3       = (unsigned short*)(base + 0);          //    163,840
    unsigned short* A         = (unsigned short*)(base + 163840);     // 12,800,000
    int*            offs      = (int*)(base + 12963840);              //    200,004
    uint2*          pkd       = (uint2*)(base + 13163848);            //  6,400,000
    uint2*          bucketed  = (uint2*)(base + 19563848);            //  6,400,000
    float4*         sorted_cf = (float4*)(base + 25963856);           // 12,800,256
    unsigned*       sorted_src= (unsigned*)(base + 38764112);         //  3,200,064
    int*            gcnt      = (int*)(base + 41964176);              //    156,800
    // total ~42.1 MB

    prep_kernel<<<3330, 256, 0, stream>>>(h, basis_w, loop_w,
                                          src, dst, etype, norm,
                                          A, wt3, pkd, gcnt,
                                          sorted_src, sorted_cf);
    binscatter<<<EP_BLOCKS, 512, 0, stream>>>(pkd, gcnt, bucketed);
    bucket_sort<<<N_RANGES, 512, 0, stream>>>(gcnt, bucketed, w_comp,
                                              sorted_src, sorted_cf, offs);
    agg_gemm<<<1563, 512, 0, stream>>>(offs, sorted_src, sorted_cf,
                                       A, wt3, bias, out);
}

// Round 9
// 179.196 us; speedup vs baseline: 1.4614x; 1.0255x over previous
//
#include <hip/hip_runtime.h>
#include <stdint.h>

#define N_NODES 50000
#define N_EDGES 800000
#define H_DIM 128
#define N_REL 40
#define N_BASES 4
#define N_RANGES 196         // node ranges of 256 (dst >> 8)
#define EP_BLOCKS 400        // edge chunks of 2000
#define EDGES_PER_BLK 2000
#define STAGE_CAP 5120       // LDS staging capacity for bucket_sort
#define CAST_BLOCKS 1563     // ceil(800000/512)

typedef __attribute__((ext_vector_type(8))) short bf16x8;
typedef __attribute__((ext_vector_type(4))) float f32x4;

// round-to-nearest-even f32 -> bf16 bits
__device__ __forceinline__ unsigned short f2bf(float f) {
    unsigned int u = __float_as_uint(f);
    unsigned int r = u + 0x7fffu + ((u >> 16) & 1u);
    return (unsigned short)(r >> 16);
}

// ---------------------------------------------------------------------------
// K0: edge_pack (400 blocks x 512, 2000 edges each). Pack edges + per-(chunk,
// bucket) LDS histogram -> gcnt[chunk][range]. Block 0 zeroes the 16-entry
// over-read pad. LDS atomics only (device atomics were a 70us stall, r7).
// pkd[e] = { src | etype<<20 , dst | nbf<<17 }  (nbf = bf16 of norm >= 0)
__global__ __launch_bounds__(512) void edge_pack(
        const int* __restrict__ src, const int* __restrict__ dst,
        const int* __restrict__ etype, const float* __restrict__ norm,
        uint2* __restrict__ pkd, int* __restrict__ gcnt,
        unsigned* __restrict__ sorted_src, float4* __restrict__ sorted_cf) {
    __shared__ int lhist[N_RANGES];
    int blk = blockIdx.x;                   // 0..399
    int t = threadIdx.x;
    if (t < N_RANGES) lhist[t] = 0;
    if (blk == 0 && t >= 496) {             // zero over-read pad
        int k = t - 496;                    // 0..15
        sorted_src[N_EDGES + k] = 0u;
        sorted_cf[N_EDGES + k] = make_float4(0.f, 0.f, 0.f, 0.f);
    }
    __syncthreads();
    int e0 = blk * EDGES_PER_BLK;
    for (int i = t; i < EDGES_PER_BLK; i += 512) {
        int e = e0 + i;
        int d = dst[e];
        unsigned int nbf = f2bf(norm[e]);   // <= 0x7FFF (norm >= 0)
        pkd[e] = make_uint2((unsigned)src[e] | ((unsigned)etype[e] << 20),
                            (unsigned)d | (nbf << 17));
        atomicAdd(&lhist[d >> 8], 1);
    }
    __syncthreads();
    if (t < N_RANGES) gcnt[blk * N_RANGES + t] = lhist[t];
}

// ---------------------------------------------------------------------------
// K1: stage2 (fused for overlap — the scatter's low machine fill is covered
// by independent streaming blocks in the SAME dispatch):
//   blocks 0..399      : binscatter chunk b -> bucket-grouped order. Bases
//                        computed in-block: t<196 column-sums gcnt[bb][t]
//                        (coalesced, L2-resident) tracking total + prefix
//                        below b; 196-wide shuffle scan -> bstart; cursor =
//                        bstart + prefix.
//   blocks 400..1962   : cast h -> A bf16 (stride 128). No dependency on K0.
//   blocks 1963..1967  : repack basis_w/loop_w into frag-major wt3.
__global__ __launch_bounds__(512) void stage2(
        const float* __restrict__ h,
        const float* __restrict__ basis_w, const float* __restrict__ loop_w,
        const uint2* __restrict__ pkd, const int* __restrict__ gcnt,
        unsigned short* __restrict__ A, unsigned short* __restrict__ wt3,
        uint2* __restrict__ bucketed) {
    __shared__ int lcur[N_RANGES];
    __shared__ int wsum[8];
    int bid = blockIdx.x;
    int t = threadIdx.x;
    if (bid < EP_BLOCKS) {
        int lane = t & 63, w = t >> 6;
        int b = bid;
        int tot = 0, pre = 0;
        if (t < N_RANGES) {
            for (int bb = 0; bb < EP_BLOCKS; ++bb) {
                int g = gcnt[bb * N_RANGES + t];
                tot += g;
                if (bb < b) pre += g;
            }
        }
        int x = (t < N_RANGES) ? tot : 0;
        int v = x;
#pragma unroll
        for (int d = 1; d < 64; d <<= 1) {
            int y = __shfl_up(v, d);
            if (lane >= d) v += y;
        }
        if (lane == 63) wsum[w] = v;
        __syncthreads();
        int wpre = 0;
#pragma unroll
        for (int ww = 0; ww < 7; ++ww)
            if (w > ww) wpre += wsum[ww];
        if (t < N_RANGES)
            lcur[t] = (wpre + v - x) + pre;     // bstart[t] + chunk-prefix
        __syncthreads();
        int e0 = b * EDGES_PER_BLK;
        for (int i = t; i < EDGES_PER_BLK; i += 512) {
            uint2 p = pkd[e0 + i];
            int r = (p.y & 0x1FFFF) >> 8;
            int pos = atomicAdd(&lcur[r], 1);
            bucketed[pos] = p;
        }
    } else if (bid < EP_BLOCKS + CAST_BLOCKS) {
        int g = (bid - EP_BLOCKS) * 512 + t;    // [0, 800256)
        if (g < 800000) {
            int row = g >> 4;
            int cb = (g & 15) * 8;
            const float* p = h + (size_t)row * 128 + cb;
            float4 a0 = ((const float4*)p)[0];
            float4 a1 = ((const float4*)p)[1];
            bf16x8 o;
            o[0] = (short)f2bf(a0.x); o[1] = (short)f2bf(a0.y);
            o[2] = (short)f2bf(a0.z); o[3] = (short)f2bf(a0.w);
            o[4] = (short)f2bf(a1.x); o[5] = (short)f2bf(a1.y);
            o[6] = (short)f2bf(a1.z); o[7] = (short)f2bf(a1.w);
            *(bf16x8*)(A + (size_t)row * H_DIM + cb) = o;
        }
    } else {
        int mat = bid - EP_BLOCKS - CAST_BLOCKS;    // 0..3 basis, 4 loop
        const float* srcm = (mat < 4) ? (basis_w + mat * 16384) : loop_w;
        int koff = (mat < 4) ? (128 + mat * 128) : 0;
#pragma unroll
        for (int i = 0; i < 8; ++i) {
            int f = t + i * 512;                // [0,4096) float4 index
            int k = f >> 5;
            int j4 = (f & 31) * 4;
            float4 v = ((const float4*)srcm)[f];
            int kg = koff + k;
            int ks = kg >> 5;
            int quad = (kg >> 3) & 3;
            int jj = kg & 7;
            float vv[4] = {v.x, v.y, v.z, v.w};
#pragma unroll
            for (int d = 0; d < 4; ++d) {
                int j = j4 + d;
                int cg = j >> 4;
                int n16 = j & 15;
                wt3[(size_t)((ks * 8 + cg) * 64 + quad * 16 + n16) * 8 + jj] =
                    f2bf(vv[d]);
            }
        }
    }
}

// ---------------------------------------------------------------------------
// K2: bucket_sort (196 blocks x 512). One block per bucket; begin/end from
// gcnt column sums + 196-wide scan. Pass 1: LDS per-dst histogram -> scan ->
// per-dst offsets (offs coalesced). Pass 2: place edges into LDS stage by
// exact sorted position, stream out coalesced as sorted_src (u32) +
// sorted_cf (float4 = w_comp[etype]*norm).
__global__ __launch_bounds__(512) void bucket_sort(
        const int* __restrict__ gcnt, const uint2* __restrict__ bucketed,
        const float* __restrict__ w_comp,
        unsigned* __restrict__ sorted_src, float4* __restrict__ sorted_cf,
        int* __restrict__ offs) {
    __shared__ int hist[256];
    __shared__ int cur[256];
    __shared__ int wsum[8];
    __shared__ int sbeg;
    __shared__ int stot;
    __shared__ uint2 stage[STAGE_CAP];
    int r = blockIdx.x;
    int t = threadIdx.x, lane = t & 63, w = t >> 6;
    int tot = 0;
    if (t < N_RANGES)
        for (int bb = 0; bb < EP_BLOCKS; ++bb)
            tot += gcnt[bb * N_RANGES + t];
    int x = (t < N_RANGES) ? tot : 0;
    int v = x;
#pragma unroll
    for (int d = 1; d < 64; d <<= 1) {
        int y = __shfl_up(v, d);
        if (lane >= d) v += y;
    }
    if (lane == 63) wsum[w] = v;
    if (t < 256) hist[t] = 0;
    __syncthreads();
    int wpre = 0;
#pragma unroll
    for (int ww = 0; ww < 7; ++ww)
        if (w > ww) wpre += wsum[ww];
    if (t == r) { sbeg = wpre + v - x; stot = x; }
    __syncthreads();
    int begin = sbeg;
    int end = begin + stot;
    int n = end - begin;
    for (int i = begin + t; i < end; i += 512)
        atomicAdd(&hist[bucketed[i].y & 255], 1);
    __syncthreads();
    int x2 = (t < 256) ? hist[t] : 0;
    int v2 = x2;
#pragma unroll
    for (int d = 1; d < 64; d <<= 1) {
        int y = __shfl_up(v2, d);
        if (lane >= d) v2 += y;
    }
    if (lane == 63) wsum[w] = v2;
    __syncthreads();
    int wpre2 = 0;
#pragma unroll
    for (int ww = 0; ww < 3; ++ww)          // only waves 0..3 hold hist
        if (w > ww) wpre2 += wsum[ww];
    if (t < 256) {
        int excl_rel = wpre2 + v2 - x2;     // position within the region
        int node = r * 256 + t;
        if (node < N_NODES) offs[node] = begin + excl_rel;
        cur[t] = excl_rel;
    }
    if (r == N_RANGES - 1 && t == 0) offs[N_NODES] = N_EDGES;
    __syncthreads();
    if (n <= STAGE_CAP) {
        for (int i = begin + t; i < end; i += 512) {
            uint2 p = bucketed[i];
            int pos = atomicAdd(&cur[p.y & 255], 1);
            stage[pos] = make_uint2(p.x, (p.y >> 17) << 16);
        }
        __syncthreads();
        for (int i = t; i < n; i += 512) {
            uint2 p = stage[i];
            float nm = __uint_as_float(p.y);
            float4 wc = ((const float4*)w_comp)[p.x >> 20];
            sorted_src[begin + i] = p.x & 0xFFFFF;
            sorted_cf[begin + i] =
                make_float4(wc.x * nm, wc.y * nm, wc.z * nm, wc.w * nm);
        }
    } else {                                    // pathological fallback
        for (int i = begin + t; i < end; i += 512) {
            uint2 p = bucketed[i];
            int pos = atomicAdd(&cur[p.y & 255], 1);
            float nm = __uint_as_float((p.y >> 17) << 16);
            float4 wc = ((const float4*)w_comp)[p.x >> 20];
            sorted_src[begin + pos] = p.x & 0xFFFFF;
            sorted_cf[begin + pos] =
                make_float4(wc.x * nm, wc.y * nm, wc.z * nm, wc.w * nm);
        }
    }
}

// ---------------------------------------------------------------------------
// K3 (fused aggregate + GEMM) — round-5 verified kernel verbatim (static
// grid 1563, VGPR=20, 49.9us; the 2-deep ping-pong was NULL in round 8 and
// is dropped). 512 threads / 8 waves, 32-node tile:
// Phase 1: wave w aggregates nodes [32*blk + 4w, +4). Edge metadata from
//   sorted_src (u32) + sorted_cf (float4, precomputed w_comp*norm) —
//   wave-uniform -> s_load batches of 8; gathers are 256B bf16 rows, 8
//   outstanding. Remainder handled by a MASKED full batch (cf=0, src=0;
//   arrays are 16-entry zero-padded) — no serial dependent tail.
//   Node's 512-wide f32 S -> bf16 -> LDS tile [32][640] (with own hbf row),
//   rows XOR-swizzled (byte ^= (row&7)<<4) for bank-uniform ds_read_b128.
// Phase 2: 32x128x640 bf16 MFMA from LDS; wave = 16 cols; bias+relu.
// Occupancy: 4 blocks/CU (LDS 40KB*4=160KB) = 32 waves/CU.
__global__ __launch_bounds__(512, 8) void agg_gemm(
        const int* __restrict__ offs, const unsigned* __restrict__ ssrc,
        const float4* __restrict__ scf,
        const unsigned short* __restrict__ Ab,
        const unsigned short* __restrict__ wt3,
        const float* __restrict__ bias, float* __restrict__ out) {
    __shared__ __align__(16) unsigned short S[32 * 640];   // 40 KB
    int wv = threadIdx.x >> 6;
    int lane = threadIdx.x & 63;
    int nbase = blockIdx.x * 32;
    const unsigned int* Au = (const unsigned int*)Ab;

#pragma unroll
    for (int q = 0; q < 4; ++q) {
        int row = (wv << 2) + q;
        int v = __builtin_amdgcn_readfirstlane(nbase + row);
        float a0l = 0.f, a0h = 0.f, a1l = 0.f, a1h = 0.f;
        float a2l = 0.f, a2h = 0.f, a3l = 0.f, a3h = 0.f;
        unsigned int hb = 0u;
        if (v < N_NODES) {
            hb = Au[(size_t)v * 64 + lane];     // own hbf row (cols 2l,2l+1)
            int begin = __builtin_amdgcn_readfirstlane(offs[v]);
            int end   = __builtin_amdgcn_readfirstlane(offs[v + 1]);
            for (int j = begin; j < end; j += 8) {
                int rem = end - j;              // uniform
                unsigned su[8];
                float4 c[8];
#pragma unroll
                for (int k = 0; k < 8; ++k) su[k] = ssrc[j + k];
#pragma unroll
                for (int k = 0; k < 8; ++k) c[k] = scf[j + k];
                if (rem < 8) {                  // uniform masked tail batch
#pragma unroll
                    for (int k = 0; k < 8; ++k)
                        if (k >= rem) {
                            su[k] = 0u;
                            c[k] = make_float4(0.f, 0.f, 0.f, 0.f);
                        }
                }
                unsigned u[8];
#pragma unroll
                for (int k = 0; k < 8; ++k)
                    u[k] = Au[(size_t)su[k] * 64 + lane];
#pragma unroll
                for (int k = 0; k < 8; ++k) {
                    float lo = __uint_as_float(u[k] << 16);
                    float hi = __uint_as_float(u[k] & 0xffff0000u);
                    a0l += c[k].x * lo; a0h += c[k].x * hi;
                    a1l += c[k].y * lo; a1h += c[k].y * hi;
                    a2l += c[k].z * lo; a2h += c[k].z * hi;
                    a3l += c[k].w * lo; a3h += c[k].w * hi;
                }
            }
        }
        // stage row into LDS: [hbf(256B) | S0 | S1 | S2 | S3], swizzled
        char* rp = (char*)S + row * 1280;
        int swz = (row & 7) << 4;
        *(unsigned int*)(rp + ((lane * 4) ^ swz)) = hb;
        *(unsigned int*)(rp + ((256 + lane * 4) ^ swz)) =
            (unsigned int)f2bf(a0l) | ((unsigned int)f2bf(a0h) << 16);
        *(unsigned int*)(rp + ((512 + lane * 4) ^ swz)) =
            (unsigned int)f2bf(a1l) | ((unsigned int)f2bf(a1h) << 16);
        *(unsigned int*)(rp + ((768 + lane * 4) ^ swz)) =
            (unsigned int)f2bf(a2l) | ((unsigned int)f2bf(a2h) << 16);
        *(unsigned int*)(rp + ((1024 + lane * 4) ^ swz)) =
            (unsigned int)f2bf(a3l) | ((unsigned int)f2bf(a3h) << 16);
    }
    __syncthreads();

    // Phase 2: rows 0..31 of LDS tile, wave wv covers cols [wv*16, wv*16+16)
    int n16 = lane & 15;
    int quad = lane >> 4;
    f32x4 acc0 = (f32x4)0.f, acc1 = (f32x4)0.f;

    const char* s0p = (const char*)S + n16 * 1280;
    const char* s1p = s0p + 16 * 1280;
    int swz2 = (n16 & 7) << 4;
    const unsigned short* bwp = wt3 + (size_t)wv * 512 + (size_t)lane * 8;

#pragma unroll
    for (int ks = 0; ks < 20; ++ks) {
        int off = (ks * 64 + quad * 16) ^ swz2;
        bf16x8 a0 = *(const bf16x8*)(s0p + off);
        bf16x8 a1 = *(const bf16x8*)(s1p + off);
        bf16x8 b  = *(const bf16x8*)(bwp + (size_t)ks * 4096);
        acc0 = __builtin_amdgcn_mfma_f32_16x16x32_bf16(a0, b, acc0, 0, 0, 0);
        acc1 = __builtin_amdgcn_mfma_f32_16x16x32_bf16(a1, b, acc1, 0, 0, 0);
    }

    // C/D layout: col = lane&15, row = quad*4 + reg
    int col = (wv << 4) + n16;
    float bv = bias[col];
#pragma unroll
    for (int rg = 0; rg < 4; ++rg) {
        int r0 = nbase + quad * 4 + rg;
        if (r0 < N_NODES)
            out[(size_t)r0 * H_DIM + col] = fmaxf(acc0[rg] + bv, 0.f);
        int r1 = nbase + 16 + quad * 4 + rg;
        if (r1 < N_NODES)
            out[(size_t)r1 * H_DIM + col] = fmaxf(acc1[rg] + bv, 0.f);
    }
}

extern "C" void kernel_launch(void* const* d_in, const int* in_sizes, int n_in,
                              void* d_out, int out_size, void* d_ws, size_t ws_size,
                              hipStream_t stream) {
    const float* h       = (const float*)d_in[0];
    const float* norm    = (const float*)d_in[1];
    const float* basis_w = (const float*)d_in[2];
    const float* w_comp  = (const float*)d_in[3];
    const float* loop_w  = (const float*)d_in[4];
    const float* bias    = (const float*)d_in[5];
    const int*   src     = (const int*)d_in[6];
    const int*   dst     = (const int*)d_in[7];
    const int*   etype   = (const int*)d_in[8];
    float* out = (float*)d_out;

    // ws layout (bytes):
    char* base = (char*)d_ws;
    unsigned short* wt3       = (unsigned short*)(base + 0);          //    163,840
    unsigned short* A         = (unsigned short*)(base + 163840);     // 12,800,000
    int*            offs      = (int*)(base + 12963840);              //    200,004
    uint2*          pkd       = (uint2*)(base + 13163848);            //  6,400,000
    uint2*          bucketed  = (uint2*)(base + 19563848);            //  6,400,000
    float4*         sorted_cf = (float4*)(base + 25963856);           // 12,800,256
    unsigned*       sorted_src= (unsigned*)(base + 38764112);         //  3,200,064
    int*            gcnt      = (int*)(base + 41964176);              //    313,600
    // total ~42.3 MB

    edge_pack<<<EP_BLOCKS, 512, 0, stream>>>(src, dst, etype, norm,
                                             pkd, gcnt,
                                             sorted_src, sorted_cf);
    stage2<<<EP_BLOCKS + CAST_BLOCKS + 5, 512, 0, stream>>>(
        h, basis_w, loop_w, pkd, gcnt, A, wt3, bucketed);
    bucket_sort<<<N_RANGES, 512, 0, stream>>>(gcnt, bucketed, w_comp,
                                              sorted_src, sorted_cf, offs);
    agg_gemm<<<1563, 512, 0, stream>>>(offs, sorted_src, sorted_cf,
                                       A, wt3, bias, out);
}

// Round 10
// 167.380 us; speedup vs baseline: 1.5646x; 1.0706x over previous
//
#include <hip/hip_runtime.h>
#include <stdint.h>

#define N_NODES 50000
#define N_EDGES 800000
#define H_DIM 128
#define N_REL 40
#define N_BASES 4
#define N_RANGES 196         // node ranges of 256 (dst >> 8)
#define EP_BLOCKS 400        // edge chunks of 2000
#define EDGES_PER_BLK 2000
#define STAGE_CAP 5120       // LDS staging capacity for bucket_sort
#define CAST_BLOCKS 1563     // ceil(800000/512)

typedef __attribute__((ext_vector_type(8))) short bf16x8;
typedef __attribute__((ext_vector_type(4))) float f32x4;

// round-to-nearest-even f32 -> bf16 bits
__device__ __forceinline__ unsigned short f2bf(float f) {
    unsigned int u = __float_as_uint(f);
    unsigned int r = u + 0x7fffu + ((u >> 16) & 1u);
    return (unsigned short)(r >> 16);
}

// ---------------------------------------------------------------------------
// K0: edge_pack (400 blocks x 1024, 2000 edges each — 2 iterations/block).
// Pack edges + per-(chunk,bucket) LDS histogram -> gcnt[chunk][range].
// Block 0 zeroes the 16-entry over-read pad. LDS atomics only.
// pkd[e] = { src | etype<<20 , dst | nbf<<17 }  (nbf = bf16 of norm >= 0)
__global__ __launch_bounds__(1024) void edge_pack(
        const int* __restrict__ src, const int* __restrict__ dst,
        const int* __restrict__ etype, const float* __restrict__ norm,
        uint2* __restrict__ pkd, int* __restrict__ gcnt,
        unsigned* __restrict__ sorted_src, float4* __restrict__ sorted_cf) {
    __shared__ int lhist[N_RANGES];
    int blk = blockIdx.x;                   // 0..399
    int t = threadIdx.x;
    if (t < N_RANGES) lhist[t] = 0;
    if (blk == 0 && t >= 1008) {            // zero over-read pad
        int k = t - 1008;                   // 0..15
        sorted_src[N_EDGES + k] = 0u;
        sorted_cf[N_EDGES + k] = make_float4(0.f, 0.f, 0.f, 0.f);
    }
    __syncthreads();
    int e0 = blk * EDGES_PER_BLK;
    for (int i = t; i < EDGES_PER_BLK; i += 1024) {
        int e = e0 + i;
        int d = dst[e];
        unsigned int nbf = f2bf(norm[e]);   // <= 0x7FFF (norm >= 0)
        pkd[e] = make_uint2((unsigned)src[e] | ((unsigned)etype[e] << 20),
                            (unsigned)d | (nbf << 17));
        atomicAdd(&lhist[d >> 8], 1);
    }
    __syncthreads();
    if (t < N_RANGES) gcnt[blk * N_RANGES + t] = lhist[t];
}

// ---------------------------------------------------------------------------
// K1: bucket_scan_a (196 blocks x 512). Block r scans its bucket's 400
// chunk-counts -> RELATIVE blkbase[chunk][range] + bucket total btot[r].
// Removes the redundant 400-iteration column-sums from the 596 downstream
// blocks (the structural regression of rounds 5-9 vs round 2).
__global__ __launch_bounds__(512) void bucket_scan_a(
        const int* __restrict__ gcnt, int* __restrict__ blkbase,
        int* __restrict__ btot) {
    __shared__ int wsum[8];
    int r = blockIdx.x;
    int t = threadIdx.x, lane = t & 63, w = t >> 6;
    int x = (t < EP_BLOCKS) ? gcnt[t * N_RANGES + r] : 0;
    int v = x;
#pragma unroll
    for (int d = 1; d < 64; d <<= 1) {
        int y = __shfl_up(v, d);
        if (lane >= d) v += y;
    }
    if (lane == 63) wsum[w] = v;
    __syncthreads();
    int wpre = 0;
#pragma unroll
    for (int ww = 0; ww < 7; ++ww)
        if (w > ww) wpre += wsum[ww];
    if (t < EP_BLOCKS) blkbase[t * N_RANGES + r] = wpre + v - x;
    if (t == 511) btot[r] = wpre + v;
}

// ---------------------------------------------------------------------------
// K2: stage2 (fused for overlap — scatter's low machine fill is covered by
// independent streaming blocks in the SAME dispatch):
//   blocks 0..399      : binscatter chunk b -> bucket-grouped order. Bases:
//                        196-wide shuffle scan of btot -> bstart; cursor =
//                        bstart + blkbase[b][range] (precomputed, coalesced).
//   blocks 400..1962   : cast h -> A bf16 (stride 128).
//   blocks 1963..1967  : repack basis_w/loop_w into frag-major wt3.
__global__ __launch_bounds__(512) void stage2(
        const float* __restrict__ h,
        const float* __restrict__ basis_w, const float* __restrict__ loop_w,
        const uint2* __restrict__ pkd, const int* __restrict__ blkbase,
        const int* __restrict__ btot,
        unsigned short* __restrict__ A, unsigned short* __restrict__ wt3,
        uint2* __restrict__ bucketed) {
    __shared__ int lcur[N_RANGES];
    __shared__ int wsum[8];
    int bid = blockIdx.x;
    int t = threadIdx.x;
    if (bid < EP_BLOCKS) {
        int lane = t & 63, w = t >> 6;
        int b = bid;
        int x = (t < N_RANGES) ? btot[t] : 0;
        int v = x;
#pragma unroll
        for (int d = 1; d < 64; d <<= 1) {
            int y = __shfl_up(v, d);
            if (lane >= d) v += y;
        }
        if (lane == 63) wsum[w] = v;
        __syncthreads();
        int wpre = 0;
#pragma unroll
        for (int ww = 0; ww < 7; ++ww)
            if (w > ww) wpre += wsum[ww];
        if (t < N_RANGES)
            lcur[t] = (wpre + v - x) + blkbase[b * N_RANGES + t];
        __syncthreads();
        int e0 = b * EDGES_PER_BLK;
        for (int i = t; i < EDGES_PER_BLK; i += 512) {
            uint2 p = pkd[e0 + i];
            int r = (p.y & 0x1FFFF) >> 8;
            int pos = atomicAdd(&lcur[r], 1);
            bucketed[pos] = p;
        }
    } else if (bid < EP_BLOCKS + CAST_BLOCKS) {
        int g = (bid - EP_BLOCKS) * 512 + t;    // [0, 800256)
        if (g < 800000) {
            int row = g >> 4;
            int cb = (g & 15) * 8;
            const float* p = h + (size_t)row * 128 + cb;
            float4 a0 = ((const float4*)p)[0];
            float4 a1 = ((const float4*)p)[1];
            bf16x8 o;
            o[0] = (short)f2bf(a0.x); o[1] = (short)f2bf(a0.y);
            o[2] = (short)f2bf(a0.z); o[3] = (short)f2bf(a0.w);
            o[4] = (short)f2bf(a1.x); o[5] = (short)f2bf(a1.y);
            o[6] = (short)f2bf(a1.z); o[7] = (short)f2bf(a1.w);
            *(bf16x8*)(A + (size_t)row * H_DIM + cb) = o;
        }
    } else {
        int mat = bid - EP_BLOCKS - CAST_BLOCKS;    // 0..3 basis, 4 loop
        const float* srcm = (mat < 4) ? (basis_w + mat * 16384) : loop_w;
        int koff = (mat < 4) ? (128 + mat * 128) : 0;
#pragma unroll
        for (int i = 0; i < 8; ++i) {
            int f = t + i * 512;                // [0,4096) float4 index
            int k = f >> 5;
            int j4 = (f & 31) * 4;
            float4 v = ((const float4*)srcm)[f];
            int kg = koff + k;
            int ks = kg >> 5;
            int quad = (kg >> 3) & 3;
            int jj = kg & 7;
            float vv[4] = {v.x, v.y, v.z, v.w};
#pragma unroll
            for (int d = 0; d < 4; ++d) {
                int j = j4 + d;
                int cg = j >> 4;
                int n16 = j & 15;
                wt3[(size_t)((ks * 8 + cg) * 64 + quad * 16 + n16) * 8 + jj] =
                    f2bf(vv[d]);
            }
        }
    }
}

// ---------------------------------------------------------------------------
// K3: bucket_sort (196 blocks x 1024 — passes halve to 4 iterations; these
// blocks are per-block-latency-bound at 0.77 blocks/CU fill). One block per
// bucket; begin from a 196-wide scan of btot (precomputed).
// Pass 1: LDS per-dst histogram -> scan -> per-dst offsets (offs coalesced).
// Pass 2: place edges into LDS stage by exact sorted position, stream out
// coalesced as sorted_src (u32) + sorted_cf (float4 = w_comp[etype]*norm).
__global__ __launch_bounds__(1024) void bucket_sort(
        const int* __restrict__ btot, const uint2* __restrict__ bucketed,
        const float* __restrict__ w_comp,
        unsigned* __restrict__ sorted_src, float4* __restrict__ sorted_cf,
        int* __restrict__ offs) {
    __shared__ int hist[256];
    __shared__ int cur[256];
    __shared__ int wsum[16];
    __shared__ int sbeg;
    __shared__ uint2 stage[STAGE_CAP];
    int r = blockIdx.x;
    int t = threadIdx.x, lane = t & 63, w = t >> 6;
    int x = (t < N_RANGES) ? btot[t] : 0;
    int v = x;
#pragma unroll
    for (int d = 1; d < 64; d <<= 1) {
        int y = __shfl_up(v, d);
        if (lane >= d) v += y;
    }
    if (lane == 63) wsum[w] = v;
    if (t < 256) hist[t] = 0;
    __syncthreads();
    int wpre = 0;
#pragma unroll
    for (int ww = 0; ww < 15; ++ww)
        if (w > ww) wpre += wsum[ww];
    if (t == r) sbeg = wpre + v - x;
    __syncthreads();
    int begin = sbeg;
    int n = btot[r];
    int end = begin + n;
    for (int i = begin + t; i < end; i += 1024)
        atomicAdd(&hist[bucketed[i].y & 255], 1);
    __syncthreads();
    int x2 = (t < 256) ? hist[t] : 0;
    int v2 = x2;
#pragma unroll
    for (int d = 1; d < 64; d <<= 1) {
        int y = __shfl_up(v2, d);
        if (lane >= d) v2 += y;
    }
    if (lane == 63) wsum[w] = v2;
    __syncthreads();
    if (t < 256) {
        int wpre2 = 0;
#pragma unroll
        for (int ww = 0; ww < 3; ++ww)      // only waves 0..3 hold hist
            if (w > ww) wpre2 += wsum[ww];
        int excl_rel = wpre2 + v2 - x2;     // position within the region
        int node = r * 256 + t;
        if (node < N_NODES) offs[node] = begin + excl_rel;
        cur[t] = excl_rel;
    }
    if (r == N_RANGES - 1 && t == 0) offs[N_NODES] = N_EDGES;
    __syncthreads();
    if (n <= STAGE_CAP) {
        for (int i = begin + t; i < end; i += 1024) {
            uint2 p = bucketed[i];
            int pos = atomicAdd(&cur[p.y & 255], 1);
            stage[pos] = make_uint2(p.x, (p.y >> 17) << 16);
        }
        __syncthreads();
        for (int i = t; i < n; i += 1024) {
            uint2 p = stage[i];
            float nm = __uint_as_float(p.y);
            float4 wc = ((const float4*)w_comp)[p.x >> 20];
            sorted_src[begin + i] = p.x & 0xFFFFF;
            sorted_cf[begin + i] =
                make_float4(wc.x * nm, wc.y * nm, wc.z * nm, wc.w * nm);
        }
    } else {                                    // pathological fallback
        for (int i = begin + t; i < end; i += 1024) {
            uint2 p = bucketed[i];
            int pos = atomicAdd(&cur[p.y & 255], 1);
            float nm = __uint_as_float((p.y >> 17) << 16);
            float4 wc = ((const float4*)w_comp)[p.x >> 20];
            sorted_src[begin + pos] = p.x & 0xFFFFF;
            sorted_cf[begin + pos] =
                make_float4(wc.x * nm, wc.y * nm, wc.z * nm, wc.w * nm);
        }
    }
}

// ---------------------------------------------------------------------------
// K4 (fused aggregate + GEMM) — round-5/9 verified kernel verbatim (static
// grid 1563, VGPR=20, ~48us; persistent wrapper and gather ping-pong were
// both shown harmful/null and are not used). 512 threads / 8 waves, 32-node
// tile. Phase 1: wave w aggregates nodes [32*blk + 4w, +4); edge metadata
// from sorted_src/sorted_cf (wave-uniform -> s_load batches of 8); gathers
// are 256B bf16 rows, 8 outstanding; MASKED full batch for the remainder.
// Node's 512-wide f32 S -> bf16 -> LDS tile [32][640] (with own hbf row),
// rows XOR-swizzled (byte ^= (row&7)<<4) for bank-uniform ds_read_b128.
// Phase 2: 32x128x640 bf16 MFMA from LDS; wave = 16 cols; bias+relu.
__global__ __launch_bounds__(512, 8) void agg_gemm(
        const int* __restrict__ offs, const unsigned* __restrict__ ssrc,
        const float4* __restrict__ scf,
        const unsigned short* __restrict__ Ab,
        const unsigned short* __restrict__ wt3,
        const float* __restrict__ bias, float* __restrict__ out) {
    __shared__ __align__(16) unsigned short S[32 * 640];   // 40 KB
    int wv = threadIdx.x >> 6;
    int lane = threadIdx.x & 63;
    int nbase = blockIdx.x * 32;
    const unsigned int* Au = (const unsigned int*)Ab;

#pragma unroll
    for (int q = 0; q < 4; ++q) {
        int row = (wv << 2) + q;
        int v = __builtin_amdgcn_readfirstlane(nbase + row);
        float a0l = 0.f, a0h = 0.f, a1l = 0.f, a1h = 0.f;
        float a2l = 0.f, a2h = 0.f, a3l = 0.f, a3h = 0.f;
        unsigned int hb = 0u;
        if (v < N_NODES) {
            hb = Au[(size_t)v * 64 + lane];     // own hbf row (cols 2l,2l+1)
            int begin = __builtin_amdgcn_readfirstlane(offs[v]);
            int end   = __builtin_amdgcn_readfirstlane(offs[v + 1]);
            for (int j = begin; j < end; j += 8) {
                int rem = end - j;              // uniform
                unsigned su[8];
                float4 c[8];
#pragma unroll
                for (int k = 0; k < 8; ++k) su[k] = ssrc[j + k];
#pragma unroll
                for (int k = 0; k < 8; ++k) c[k] = scf[j + k];
                if (rem < 8) {                  // uniform masked tail batch
#pragma unroll
                    for (int k = 0; k < 8; ++k)
                        if (k >= rem) {
                            su[k] = 0u;
                            c[k] = make_float4(0.f, 0.f, 0.f, 0.f);
                        }
                }
                unsigned u[8];
#pragma unroll
                for (int k = 0; k < 8; ++k)
                    u[k] = Au[(size_t)su[k] * 64 + lane];
#pragma unroll
                for (int k = 0; k < 8; ++k) {
                    float lo = __uint_as_float(u[k] << 16);
                    float hi = __uint_as_float(u[k] & 0xffff0000u);
                    a0l += c[k].x * lo; a0h += c[k].x * hi;
                    a1l += c[k].y * lo; a1h += c[k].y * hi;
                    a2l += c[k].z * lo; a2h += c[k].z * hi;
                    a3l += c[k].w * lo; a3h += c[k].w * hi;
                }
            }
        }
        // stage row into LDS: [hbf(256B) | S0 | S1 | S2 | S3], swizzled
        char* rp = (char*)S + row * 1280;
        int swz = (row & 7) << 4;
        *(unsigned int*)(rp + ((lane * 4) ^ swz)) = hb;
        *(unsigned int*)(rp + ((256 + lane * 4) ^ swz)) =
            (unsigned int)f2bf(a0l) | ((unsigned int)f2bf(a0h) << 16);
        *(unsigned int*)(rp + ((512 + lane * 4) ^ swz)) =
            (unsigned int)f2bf(a1l) | ((unsigned int)f2bf(a1h) << 16);
        *(unsigned int*)(rp + ((768 + lane * 4) ^ swz)) =
            (unsigned int)f2bf(a2l) | ((unsigned int)f2bf(a2h) << 16);
        *(unsigned int*)(rp + ((1024 + lane * 4) ^ swz)) =
            (unsigned int)f2bf(a3l) | ((unsigned int)f2bf(a3h) << 16);
    }
    __syncthreads();

    // Phase 2: rows 0..31 of LDS tile, wave wv covers cols [wv*16, wv*16+16)
    int n16 = lane & 15;
    int quad = lane >> 4;
    f32x4 acc0 = (f32x4)0.f, acc1 = (f32x4)0.f;

    const char* s0p = (const char*)S + n16 * 1280;
    const char* s1p = s0p + 16 * 1280;
    int swz2 = (n16 & 7) << 4;
    const unsigned short* bwp = wt3 + (size_t)wv * 512 + (size_t)lane * 8;

#pragma unroll
    for (int ks = 0; ks < 20; ++ks) {
        int off = (ks * 64 + quad * 16) ^ swz2;
        bf16x8 a0 = *(const bf16x8*)(s0p + off);
        bf16x8 a1 = *(const bf16x8*)(s1p + off);
        bf16x8 b  = *(const bf16x8*)(bwp + (size_t)ks * 4096);
        acc0 = __builtin_amdgcn_mfma_f32_16x16x32_bf16(a0, b, acc0, 0, 0, 0);
        acc1 = __builtin_amdgcn_mfma_f32_16x16x32_bf16(a1, b, acc1, 0, 0, 0);
    }

    // C/D layout: col = lane&15, row = quad*4 + reg
    int col = (wv << 4) + n16;
    float bv = bias[col];
#pragma unroll
    for (int rg = 0; rg < 4; ++rg) {
        int r0 = nbase + quad * 4 + rg;
        if (r0 < N_NODES)
            out[(size_t)r0 * H_DIM + col] = fmaxf(acc0[rg] + bv, 0.f);
        int r1 = nbase + 16 + quad * 4 + rg;
        if (r1 < N_NODES)
            out[(size_t)r1 * H_DIM + col] = fmaxf(acc1[rg] + bv, 0.f);
    }
}

extern "C" void kernel_launch(void* const* d_in, const int* in_sizes, int n_in,
                              void* d_out, int out_size, void* d_ws, size_t ws_size,
                              hipStream_t stream) {
    const float* h       = (const float*)d_in[0];
    const float* norm    = (const float*)d_in[1];
    const float* basis_w = (const float*)d_in[2];
    const float* w_comp  = (const float*)d_in[3];
    const float* loop_w  = (const float*)d_in[4];
    const float* bias    = (const float*)d_in[5];
    const int*   src     = (const int*)d_in[6];
    const int*   dst     = (const int*)d_in[7];
    const int*   etype   = (const int*)d_in[8];
    float* out = (float*)d_out;

    // ws layout (bytes):
    char* base = (char*)d_ws;
    unsigned short* wt3       = (unsigned short*)(base + 0);          //    163,840
    unsigned short* A         = (unsigned short*)(base + 163840);     // 12,800,000
    int*            offs      = (int*)(base + 12963840);              //    200,004
    uint2*          pkd       = (uint2*)(base + 13163848);            //  6,400,000
    uint2*          bucketed  = (uint2*)(base + 19563848);            //  6,400,000
    float4*         sorted_cf = (float4*)(base + 25963856);           // 12,800,256
    unsigned*       sorted_src= (unsigned*)(base + 38764112);         //  3,200,064
    int*            gcnt      = (int*)(base + 41964176);              //    313,600
    int*            blkbase   = (int*)(base + 42277776);              //    313,600
    int*            btot      = (int*)(base + 42591376);              //        784
    // total ~42.6 MB

    edge_pack<<<EP_BLOCKS, 1024, 0, stream>>>(src, dst, etype, norm,
                                              pkd, gcnt,
                                              sorted_src, sorted_cf);
    bucket_scan_a<<<N_RANGES, 512, 0, stream>>>(gcnt, blkbase, btot);
    stage2<<<EP_BLOCKS + CAST_BLOCKS + 5, 512, 0, stream>>>(
        h, basis_w, loop_w, pkd, blkbase, btot, A, wt3, bucketed);
    bucket_sort<<<N_RANGES, 1024, 0, stream>>>(btot, bucketed, w_comp,
                                               sorted_src, sorted_cf, offs);
    agg_gemm<<<1563, 512, 0, stream>>>(offs, sorted_src, sorted_cf,
                                       A, wt3, bias, out);
}